// Round 1
// baseline (91.018 us; speedup 1.0000x reference)
//
#include <hip/hip_runtime.h>

constexpr int D_  = 1024;  // embedding dim
constexpr int E_  = 64;    // experts
constexpr int N_  = 1024;  // B*S tokens
constexpr int TG_ = 32;    // token group per pass
constexpr int DC_ = 128;   // d-chunk staged in LDS

// ---------------- bucket tokens by expert ----------------
__global__ __launch_bounds__(1024) void bucket_kernel(const int* __restrict__ urls,
                                                      int* __restrict__ offs,
                                                      int* __restrict__ toks) {
  __shared__ int cnt[E_];
  __shared__ int offsh[E_ + 1];
  __shared__ int cur[E_];
  const int tid = threadIdx.x;
  if (tid < E_) cnt[tid] = 0;
  __syncthreads();
  const int u = urls[tid];
  atomicAdd(&cnt[u], 1);
  __syncthreads();
  if (tid == 0) {
    int run = 0;
    for (int e = 0; e < E_; ++e) { offsh[e] = run; cur[e] = run; run += cnt[e]; }
    offsh[E_] = run;
  }
  __syncthreads();
  const int pos = atomicAdd(&cur[u], 1);
  toks[pos] = tid;
  if (tid <= E_) offs[tid] = offsh[tid];
}

// ---------------- grouped GEMM: one block = (k-slice, expert) ----------------
template <int KS>
__global__ __launch_bounds__(256, 2) void gemm_kernel(
    const float* __restrict__ x, const float* __restrict__ trans,
    const int* __restrict__ offs, const int* __restrict__ toks_g,
    float* __restrict__ partial) {
  constexpr int K = D_ / KS;
  __shared__ float xs[TG_][DC_];
  __shared__ int toks[TG_];
  const int tid = threadIdx.x;
  const int ks  = blockIdx.x;
  const int e   = blockIdx.y;
  const int d0  = ks * K;
  const int beg0 = offs[e];
  const int end  = offs[e + 1];
  const float* __restrict__ tr = trans + (size_t)e * D_ * D_;

  for (int beg = beg0; beg < end; beg += TG_) {
    const int T = (end - beg < TG_) ? (end - beg) : TG_;
    const int nOct = (T + 7) >> 3;
    if (tid < TG_) toks[tid] = (tid < T) ? toks_g[beg + tid] : 0;

    float4 acc[TG_];
#pragma unroll
    for (int t = 0; t < TG_; ++t) acc[t] = make_float4(0.f, 0.f, 0.f, 0.f);

    for (int dc = 0; dc < K; dc += DC_) {
      __syncthreads();  // xs safe to overwrite; toks visible
#pragma unroll
      for (int i = 0; i < (TG_ * DC_ / 4) / 256; ++i) {  // 4 float4 per thread
        const int e4 = tid + i * 256;
        const int t  = e4 >> 5;        // DC_/4 = 32 float4 per row
        const int dq = e4 & 31;
        float4 v = make_float4(0.f, 0.f, 0.f, 0.f);
        if (t < T) v = *(const float4*)&x[(size_t)toks[t] * D_ + d0 + dc + dq * 4];
        *(float4*)&xs[t][dq * 4] = v;
      }
      __syncthreads();

      for (int dd4 = 0; dd4 < DC_ / 4; ++dd4) {
        const int dd = d0 + dc + dd4 * 4;
        const float4 w0 = *(const float4*)&tr[(size_t)(dd + 0) * D_ + tid * 4];
        const float4 w1 = *(const float4*)&tr[(size_t)(dd + 1) * D_ + tid * 4];
        const float4 w2 = *(const float4*)&tr[(size_t)(dd + 2) * D_ + tid * 4];
        const float4 w3 = *(const float4*)&tr[(size_t)(dd + 3) * D_ + tid * 4];
#pragma unroll
        for (int oct = 0; oct < TG_ / 8; ++oct) {
          if (oct < nOct) {  // uniform branch: skip empty token octets
#pragma unroll
            for (int j = 0; j < 8; ++j) {
              const int t = oct * 8 + j;
              const float4 xv = *(const float4*)&xs[t][dd4 * 4];
              acc[t].x += xv.x * w0.x + xv.y * w1.x + xv.z * w2.x + xv.w * w3.x;
              acc[t].y += xv.x * w0.y + xv.y * w1.y + xv.z * w2.y + xv.w * w3.y;
              acc[t].z += xv.x * w0.z + xv.y * w1.z + xv.z * w2.z + xv.w * w3.z;
              acc[t].w += xv.x * w0.w + xv.y * w1.w + xv.z * w2.w + xv.w * w3.w;
            }
          }
        }
      }
    }

#pragma unroll
    for (int t = 0; t < TG_; ++t) {
      if (t < T) {
        const size_t row = (size_t)ks * N_ + (size_t)(beg + t);
        *(float4*)&partial[row * D_ + tid * 4] = acc[t];
      }
    }
  }
}

// ---------------- reduce k-slices + bias + tanh, scatter to out ----------------
__global__ __launch_bounds__(256) void epilogue_kernel(
    const float* __restrict__ partial, const float* __restrict__ bias,
    const int* __restrict__ urls, const int* __restrict__ toks,
    float* __restrict__ out, int KSr) {
  const int gid  = blockIdx.x * 256 + threadIdx.x;  // over N_*D_/4
  const int slot = gid >> 8;                        // 256 float4 per row
  const int c4   = (gid & 255) * 4;
  const int n = toks[slot];
  const int u = urls[n];
  float sx = 0.f, sy = 0.f, sz = 0.f, sw = 0.f;
  for (int ks = 0; ks < KSr; ++ks) {
    const float4 p = *(const float4*)&partial[((size_t)ks * N_ + slot) * D_ + c4];
    sx += p.x; sy += p.y; sz += p.z; sw += p.w;
  }
  const float4 b = *(const float4*)&bias[(size_t)u * D_ + c4];
  float4 o;
  o.x = tanhf(sx + b.x);
  o.y = tanhf(sy + b.y);
  o.z = tanhf(sz + b.z);
  o.w = tanhf(sw + b.w);
  *(float4*)&out[(size_t)n * D_ + c4] = o;
}

extern "C" void kernel_launch(void* const* d_in, const int* in_sizes, int n_in,
                              void* d_out, int out_size, void* d_ws, size_t ws_size,
                              hipStream_t stream) {
  const float* x     = (const float*)d_in[0];
  const int*   urls  = (const int*)d_in[1];
  const float* trans = (const float*)d_in[2];
  const float* bias  = (const float*)d_in[3];
  float* out = (float*)d_out;

  char* ws = (char*)d_ws;
  int* offs = (int*)ws;                 // 65 ints
  int* toks = (int*)(ws + 512);         // 1024 ints
  float* partial = (float*)(ws + 8192); // KS * 4 MB

  const size_t slice = (size_t)N_ * D_ * sizeof(float);
  int KS = 8;
  if (ws_size < 8192 + 8 * slice) KS = 4;
  if (ws_size < 8192 + 4 * slice) KS = 2;
  if (ws_size < 8192 + 2 * slice) KS = 1;

  bucket_kernel<<<1, 1024, 0, stream>>>(urls, offs, toks);

  dim3 grid(KS, E_);
  switch (KS) {
    case 8: gemm_kernel<8><<<grid, 256, 0, stream>>>(x, trans, offs, toks, partial); break;
    case 4: gemm_kernel<4><<<grid, 256, 0, stream>>>(x, trans, offs, toks, partial); break;
    case 2: gemm_kernel<2><<<grid, 256, 0, stream>>>(x, trans, offs, toks, partial); break;
    default: gemm_kernel<1><<<grid, 256, 0, stream>>>(x, trans, offs, toks, partial); break;
  }

  epilogue_kernel<<<(N_ * D_ / 4) / 256, 256, 0, stream>>>(partial, bias, urls, toks, out, KS);
}

// Round 2
// 86.921 us; speedup vs baseline: 1.0471x; 1.0471x over previous
//
#include <hip/hip_runtime.h>

constexpr int D_  = 1024;  // embedding dim
constexpr int E_  = 64;    // experts
constexpr int N_  = 1024;  // B*S tokens
constexpr int TG  = 32;    // tokens per pass (>= typical max bucket)
constexpr int CS  = 8;     // column slices (blocks per expert)
constexpr int CPB = D_ / CS;   // 128 cols per block
constexpr int KG  = 8;     // k-groups within block (tid>>5)
constexpr int KR  = D_ / KG;   // 128 k-rows per group
constexpr int DC  = 64;    // staged rows per chunk per group
constexpr int NC  = KR / DC;   // 2 chunks

// One block = (col-slice cs, expert e). 256 threads = 8 k-groups x 32 col-threads.
// Each thread: 4 consecutive output cols, 1/8 of K. LDS reduce across k-groups,
// fused bias + tanh + scatter-store. trans is streamed from HBM exactly once.
__global__ __launch_bounds__(256, 2) void fused_moe_kernel(
    const float* __restrict__ x, const int* __restrict__ urls,
    const float* __restrict__ trans, const float* __restrict__ bias,
    float* __restrict__ out) {
  __shared__ __align__(16) float xs[KG][TG][DC];  // 64 KB; overlaid as reduce buf
  __shared__ int toksL[N_];                       // 4 KB
  __shared__ int cntS;

  const int tid = threadIdx.x;
  const int cs  = blockIdx.x;
  const int e   = blockIdx.y;
  const int kg  = tid >> 5;   // 0..7
  const int ct  = tid & 31;   // 0..31
  const int c0  = cs * CPB;

  // ---- in-block bucketing: list of tokens routed to expert e ----
  if (tid == 0) cntS = 0;
  __syncthreads();
  for (int i = tid; i < N_; i += 256) {
    if (urls[i] == e) { int p = atomicAdd(&cntS, 1); toksL[p] = i; }
  }
  __syncthreads();
  const int Ttot = cntS;

  const float* __restrict__ tr = trans + (size_t)e * D_ * D_ + c0;

  for (int beg = 0; beg < Ttot; beg += TG) {
    const int T    = (Ttot - beg < TG) ? (Ttot - beg) : TG;
    const int nOct = (T + 7) >> 3;

    float4 acc[TG];
#pragma unroll
    for (int t = 0; t < TG; ++t) acc[t] = make_float4(0.f, 0.f, 0.f, 0.f);

    for (int c = 0; c < NC; ++c) {
      __syncthreads();  // xs free (prev compute/reduce reads done)
      // stage: KG*TG*DC floats = 4096 float4 -> 16 per thread, contiguous writes
#pragma unroll
      for (int it = 0; it < 16; ++it) {
        const int i  = tid + it * 256;
        const int j4 = i & 15;          // float4 within row (DC/4 = 16)
        const int t  = (i >> 4) & 31;   // token slot
        const int g  = i >> 9;          // k-group
        float4 v = make_float4(0.f, 0.f, 0.f, 0.f);
        if (t < T)
          v = *(const float4*)&x[(size_t)toksL[beg + t] * D_ + g * KR + c * DC + j4 * 4];
        *(float4*)&xs[g][t][j4 * 4] = v;
      }
      __syncthreads();

      for (int dd4 = 0; dd4 < DC / 4; ++dd4) {
        const size_t rb = (size_t)(kg * KR + c * DC + dd4 * 4) * D_ + ct * 4;
        const float4 w0 = *(const float4*)&tr[rb];
        const float4 w1 = *(const float4*)&tr[rb + D_];
        const float4 w2 = *(const float4*)&tr[rb + 2 * (size_t)D_];
        const float4 w3 = *(const float4*)&tr[rb + 3 * (size_t)D_];
#pragma unroll
        for (int oct = 0; oct < TG / 8; ++oct) {
          if (oct < nOct) {  // uniform: skip empty token octets
#pragma unroll
            for (int j = 0; j < 8; ++j) {
              const int t = oct * 8 + j;
              const float4 xv = *(const float4*)&xs[kg][t][dd4 * 4];  // broadcast
              acc[t].x += xv.x * w0.x + xv.y * w1.x + xv.z * w2.x + xv.w * w3.x;
              acc[t].y += xv.x * w0.y + xv.y * w1.y + xv.z * w2.y + xv.w * w3.y;
              acc[t].z += xv.x * w0.z + xv.y * w1.z + xv.z * w2.z + xv.w * w3.z;
              acc[t].w += xv.x * w0.w + xv.y * w1.w + xv.z * w2.w + xv.w * w3.w;
            }
          }
        }
      }
    }

    // ---- LDS reduce across k-groups + bias + tanh + store (4 rounds x 8 tokens) ----
    float4* red = (float4*)&xs[0][0][0];  // [KG][32][9] float4 (9 = +1 pad)
    const int tt_r = tid >> 5;            // token-in-round 0..7
    const int ct_r = tid & 31;
    __syncthreads();                      // all xs reads done before overlay
#pragma unroll
    for (int r = 0; r < TG / 8; ++r) {
#pragma unroll
      for (int tt = 0; tt < 8; ++tt)
        red[(kg * 32 + ct) * 9 + tt] = acc[r * 8 + tt];
      __syncthreads();
      const int slot = r * 8 + tt_r;
      if (slot < T) {
        float4 s = make_float4(0.f, 0.f, 0.f, 0.f);
#pragma unroll
        for (int g = 0; g < KG; ++g) {
          const float4 p = red[(g * 32 + ct_r) * 9 + tt_r];
          s.x += p.x; s.y += p.y; s.z += p.z; s.w += p.w;
        }
        const int tok = toksL[beg + slot];
        const int u   = urls[tok];
        const float4 b = *(const float4*)&bias[(size_t)u * D_ + c0 + ct_r * 4];
        float4 o;
        o.x = tanhf(s.x + b.x);
        o.y = tanhf(s.y + b.y);
        o.z = tanhf(s.z + b.z);
        o.w = tanhf(s.w + b.w);
        *(float4*)&out[(size_t)tok * D_ + c0 + ct_r * 4] = o;
      }
      __syncthreads();  // red slots free before next round's writes
    }
  }
}

extern "C" void kernel_launch(void* const* d_in, const int* in_sizes, int n_in,
                              void* d_out, int out_size, void* d_ws, size_t ws_size,
                              hipStream_t stream) {
  const float* x     = (const float*)d_in[0];
  const int*   urls  = (const int*)d_in[1];
  const float* trans = (const float*)d_in[2];
  const float* bias  = (const float*)d_in[3];
  float* out = (float*)d_out;

  dim3 grid(CS, E_);
  fused_moe_kernel<<<grid, 256, 0, stream>>>(x, urls, trans, bias, out);
}

// Round 3
// 75.033 us; speedup vs baseline: 1.2130x; 1.1584x over previous
//
#include <hip/hip_runtime.h>

constexpr int D_  = 1024;  // embedding dim
constexpr int E_  = 64;    // experts
constexpr int N_  = 1024;  // B*S tokens
constexpr int TG  = 32;    // tokens per pass (>= typical max bucket)
constexpr int CS  = 16;    // column slices (blocks per expert)
constexpr int CPB = D_ / CS;   // 64 cols per block
constexpr int KG  = 8;     // k-groups within block (tid>>5)
constexpr int KR  = D_ / KG;   // 128 k-rows per group
constexpr int DC  = 32;    // staged rows per chunk per group
constexpr int NC  = KR / DC;   // 4 chunks

// One block = (col-slice cs, expert e). 256 threads = 8 k-groups x 32 col-threads.
// Each thread: 2 consecutive output cols (float2), 1/8 of K. LDS reduce across
// k-groups, fused bias + tanh + scatter-store. trans streamed from HBM once.
__global__ __launch_bounds__(256, 4) void fused_moe_kernel(
    const float* __restrict__ x, const int* __restrict__ urls,
    const float* __restrict__ trans, const float* __restrict__ bias,
    float* __restrict__ out) {
  __shared__ __align__(16) float xs[KG][TG][DC];  // 32 KB; overlaid as reduce buf
  __shared__ int toksL[N_];                       // 4 KB
  __shared__ int cntS;

  const int tid = threadIdx.x;
  const int cs  = blockIdx.x;
  const int e   = blockIdx.y;
  const int kg  = tid >> 5;   // 0..7
  const int ct  = tid & 31;   // 0..31
  const int c0  = cs * CPB;

  // ---- in-block bucketing: list of tokens routed to expert e ----
  if (tid == 0) cntS = 0;
  __syncthreads();
  for (int i = tid; i < N_; i += 256) {
    if (urls[i] == e) { int p = atomicAdd(&cntS, 1); toksL[p] = i; }
  }
  __syncthreads();
  const int Ttot = cntS;

  const float* __restrict__ tr = trans + (size_t)e * D_ * D_ + c0;

  for (int beg = 0; beg < Ttot; beg += TG) {
    const int T    = (Ttot - beg < TG) ? (Ttot - beg) : TG;
    const int nOct = (T + 7) >> 3;

    float2 acc[TG];
#pragma unroll
    for (int t = 0; t < TG; ++t) acc[t] = make_float2(0.f, 0.f);

    for (int c = 0; c < NC; ++c) {
      __syncthreads();  // xs free (prev reads done)
      // stage: KG*TG*DC floats = 2048 float4 -> 8 per thread
#pragma unroll
      for (int it = 0; it < 8; ++it) {
        const int i  = tid + it * 256;
        const int j4 = i & 7;           // float4 within row (DC/4 = 8)
        const int t  = (i >> 3) & 31;   // token slot
        const int g  = i >> 8;          // k-group
        float4 v = make_float4(0.f, 0.f, 0.f, 0.f);
        if (t < T)
          v = *(const float4*)&x[(size_t)toksL[beg + t] * D_ + g * KR + c * DC + j4 * 4];
        *(float4*)&xs[g][t][j4 * 4] = v;
      }
      __syncthreads();

      for (int dd4 = 0; dd4 < DC / 4; ++dd4) {
        const size_t rb = (size_t)(kg * KR + c * DC + dd4 * 4) * D_ + ct * 2;
        const float2 w0 = *(const float2*)&tr[rb];
        const float2 w1 = *(const float2*)&tr[rb + D_];
        const float2 w2 = *(const float2*)&tr[rb + 2 * (size_t)D_];
        const float2 w3 = *(const float2*)&tr[rb + 3 * (size_t)D_];
#pragma unroll
        for (int oct = 0; oct < TG / 8; ++oct) {
          if (oct < nOct) {  // uniform: skip empty token octets
#pragma unroll
            for (int j = 0; j < 8; ++j) {
              const int t = oct * 8 + j;
              const float4 xv = *(const float4*)&xs[kg][t][dd4 * 4];  // broadcast
              acc[t].x += xv.x * w0.x + xv.y * w1.x + xv.z * w2.x + xv.w * w3.x;
              acc[t].y += xv.x * w0.y + xv.y * w1.y + xv.z * w2.y + xv.w * w3.y;
            }
          }
        }
      }
    }

    // ---- LDS reduce across k-groups + bias + tanh + store (4 rounds x 8 tokens) ----
    float2* red = (float2*)&xs[0][0][0];  // [KG][32][9] float2 (9 = +1 pad) = 18 KB
    const int tt_r = tid >> 5;            // token-in-round 0..7
    const int ct_r = tid & 31;
    __syncthreads();                      // all xs reads done before overlay
#pragma unroll
    for (int r = 0; r < TG / 8; ++r) {
#pragma unroll
      for (int tt = 0; tt < 8; ++tt)
        red[(kg * 32 + ct) * 9 + tt] = acc[r * 8 + tt];
      __syncthreads();
      const int slot = r * 8 + tt_r;
      if (slot < T) {
        float2 s = make_float2(0.f, 0.f);
#pragma unroll
        for (int g = 0; g < KG; ++g) {
          const float2 p = red[(g * 32 + ct_r) * 9 + tt_r];
          s.x += p.x; s.y += p.y;
        }
        const int tok = toksL[beg + slot];
        const int u   = urls[tok];
        const float2 b = *(const float2*)&bias[(size_t)u * D_ + c0 + ct_r * 2];
        float2 o;
        o.x = tanhf(s.x + b.x);
        o.y = tanhf(s.y + b.y);
        *(float2*)&out[(size_t)tok * D_ + c0 + ct_r * 2] = o;
      }
      __syncthreads();  // red slots free before next round's writes
    }
  }
}

extern "C" void kernel_launch(void* const* d_in, const int* in_sizes, int n_in,
                              void* d_out, int out_size, void* d_ws, size_t ws_size,
                              hipStream_t stream) {
  const float* x     = (const float*)d_in[0];
  const int*   urls  = (const int*)d_in[1];
  const float* trans = (const float*)d_in[2];
  const float* bias  = (const float*)d_in[3];
  float* out = (float*)d_out;

  dim3 grid(CS, E_);
  fused_moe_kernel<<<grid, 256, 0, stream>>>(x, urls, trans, bias, out);
}